// Round 1
// baseline (374.967 us; speedup 1.0000x reference)
//
#include <hip/hip_runtime.h>

typedef __attribute__((ext_vector_type(8))) short short8;
typedef __attribute__((ext_vector_type(4))) float floatx4;

#define B_ 2
#define T_ 2048
#define DM_ 2048
#define H_ 16
#define D_ 128
#define HALF_ 64

__device__ inline unsigned short f2bf(float f) {
    union { float f; unsigned u; } v; v.f = f;
    unsigned r = (v.u + 0x7fffu + ((v.u >> 16) & 1u)) >> 16;
    return (unsigned short)r;
}

__device__ inline void gld16(const void* g, void* l) {
    __builtin_amdgcn_global_load_lds(
        (__attribute__((address_space(1))) void*)g,
        (__attribute__((address_space(3))) void*)l,
        16, 0, 0);
}

// ---------------- fused fp32 -> bf16 convert: x (2 slices) + 4 weights ----------------
__global__ void conv_all(const float* __restrict__ x,
                         const float* __restrict__ w0, const float* __restrict__ w1,
                         const float* __restrict__ w2, const float* __restrict__ w3,
                         unsigned short* __restrict__ xb,
                         unsigned short* __restrict__ wb, int n4w) {
    int y = blockIdx.y;
    int i = blockIdx.x * 256 + threadIdx.x;
    const float* src;
    ushort4* dst;
    if (y < 2) { src = x + (size_t)y * n4w * 4; dst = (ushort4*)xb + (size_t)y * n4w; }
    else {
        src = (y == 2) ? w0 : (y == 3) ? w1 : (y == 4) ? w2 : w3;
        dst = (ushort4*)wb + (size_t)(y - 2) * n4w;
    }
    float4 f = ((const float4*)src)[i];
    ushort4 o;
    o.x = f2bf(f.x); o.y = f2bf(f.y); o.z = f2bf(f.z); o.w = f2bf(f.w);
    dst[i] = o;
}

// ---------------- fused QKV GEMM + RoPE + V-transpose: 256x256 tile, 8-phase ----------
// grid (24, 16), 512 threads = 8 waves (2M x 4N). W = [wq|wk|wv] (6144 x 2048, B^T).
// BK=64. LDS 128 KiB: A dbuf 2x(2 halves of 128x64) at 0, B same at +32768 shorts.
// Swizzle: 16B chunk phys = logical ^ (row&7) (proven pattern from 128^2 version).
// Per-wave cols are non-contiguous within head: {o..o+32} U {o+64..o+96} so RoPE pairs
// (dh, dh+64) are acc[mf][nf]/acc[mf][nf+2] in-register.
// Counted vmcnt gates: vmcnt(4) end of phase 1 (A i1 halves), vmcnt(2) end of phase 3.

#define STG(dstoff, srcp, grow0, ii)                                        \
    { int g_ = (ii) * 512 + t; int m_ = g_ >> 3, c_ = g_ & 7;               \
      int k8_ = c_ ^ (m_ & 7);                                              \
      gld16((srcp) + (size_t)((grow0) + m_) * K + (size_t)ktn * 64 + k8_ * 8, \
            sh + (dstoff) + ((ii) * 512 + (t & ~63)) * 8); }

#define DS_A(PH)                                                            \
    { _Pragma("unroll") for (int j = 0; j < 2; ++j) {                       \
        int row_ = (2 * (PH) + j) * 16 + l15;                               \
        _Pragma("unroll") for (int s = 0; s < 2; ++s) {                     \
            int pc_ = (quad + s * 4) ^ (row_ & 7);                          \
            a[j][s] = *(const short8*)(sh + aoff + row_ * 64 + pc_ * 8); } } }

#define MM(PH)                                                              \
    { _Pragma("unroll") for (int j = 0; j < 2; ++j)                         \
      _Pragma("unroll") for (int nf = 0; nf < 4; ++nf)                      \
      _Pragma("unroll") for (int s = 0; s < 2; ++s)                         \
        acc[2 * (PH) + j][nf] = __builtin_amdgcn_mfma_f32_16x16x32_bf16(    \
            a[j][s], b[nf][s], acc[2 * (PH) + j][nf], 0, 0, 0); }

#define PHASE_MID()                                                         \
    __builtin_amdgcn_s_barrier();                                           \
    asm volatile("s_waitcnt lgkmcnt(0)" ::: "memory");                      \
    __builtin_amdgcn_sched_barrier(0);                                      \
    __builtin_amdgcn_s_setprio(1);

#define PHASE_END()                                                         \
    __builtin_amdgcn_s_setprio(0);                                          \
    __builtin_amdgcn_s_barrier();

__global__ __launch_bounds__(512, 2)
void gemm_qkv(const unsigned short* __restrict__ A,
              const unsigned short* __restrict__ W,
              unsigned short* __restrict__ q,
              unsigned short* __restrict__ k,
              unsigned short* __restrict__ vt,
              const float* __restrict__ cosT,
              const float* __restrict__ sinT) {
    __shared__ unsigned short sh[65536];   // 128 KiB

    const int t    = threadIdx.x;          // 0..511
    const int lane = t & 63;
    const int w    = t >> 6;               // 0..7
    const int wm   = w >> 2;               // 0..1  M half
    const int wn   = w & 3;                // 0..3
    const int bh   = wn >> 1;              // B half (head within block)
    const int wodd = wn & 1;               // 32-col offset within half
    const int l15  = lane & 15, quad = lane >> 4;
    const int bx   = blockIdx.x;           // 0..23
    const int row0 = blockIdx.y * 256;
    const int col0 = bx * 256;
    const int K    = DM_;

    floatx4 acc[8][4];
#pragma unroll
    for (int i = 0; i < 8; ++i)
#pragma unroll
        for (int j = 0; j < 4; ++j)
            acc[i][j] = (floatx4){0.f, 0.f, 0.f, 0.f};

    // ---- prologue: stage K-tile 0 into buf0 (order: B0,B0,B1,B1,A0i0,A1i0,A0i1,A1i1)
    {
        const int ktn = 0;
        STG(32768,        W, col0,       0);
        STG(32768,        W, col0,       1);
        STG(32768 + 8192, W, col0 + 128, 0);
        STG(32768 + 8192, W, col0 + 128, 1);
        STG(0,            A, row0,       0);
        STG(8192,         A, row0 + 128, 0);
        STG(0,            A, row0,       1);
        STG(8192,         A, row0 + 128, 1);
    }
    asm volatile("s_waitcnt vmcnt(2)" ::: "memory");   // A i1 halves may still fly
    __builtin_amdgcn_s_barrier();

    for (int kt = 0; kt < 32; ++kt) {
        const int cb   = kt & 1, nb = cb ^ 1;
        const int ktn  = (kt < 31) ? kt + 1 : 31;      // clamp: last windows re-stage tile 31
        const int aoff = cb * 16384 + wm * 8192;
        const int boff = 32768 + cb * 16384 + bh * 8192;
        const int nbA  = nb * 16384;
        const int nbB  = 32768 + nb * 16384;
        short8 a[2][2];
        short8 b[4][2];

        // ---- phase 0: b[4][2] + a(mf0,1); stage B-half0(kt+1)
#pragma unroll
        for (int nf = 0; nf < 4; ++nf) {
            int lc = wodd * 32 + (nf & 1) * 16 + (nf >> 1) * 64 + l15;
#pragma unroll
            for (int s = 0; s < 2; ++s) {
                int pc = (quad + s * 4) ^ (lc & 7);
                b[nf][s] = *(const short8*)(sh + boff + lc * 64 + pc * 8);
            }
        }
        DS_A(0)
        STG(nbB, W, col0, 0);
        STG(nbB, W, col0, 1);
        PHASE_MID()
        MM(0)
        PHASE_END()

        // ---- phase 1: a(mf2,3); stage B-half1(kt+1); gate A(kt) i1 halves
        DS_A(1)
        STG(nbB + 8192, W, col0 + 128, 0);
        STG(nbB + 8192, W, col0 + 128, 1);
        PHASE_MID()
        MM(1)
        __builtin_amdgcn_s_setprio(0);
        asm volatile("s_waitcnt vmcnt(4)" ::: "memory");
        __builtin_amdgcn_s_barrier();

        // ---- phase 2: a(mf4,5); stage A-i0 halves (kt+1)
        DS_A(2)
        STG(nbA,        A, row0,       0);
        STG(nbA + 8192, A, row0 + 128, 0);
        PHASE_MID()
        MM(2)
        PHASE_END()

        // ---- phase 3: a(mf6,7); stage A-i1 halves (kt+1); gate K-tile kt+1
        DS_A(3)
        STG(nbA,        A, row0,       1);
        STG(nbA + 8192, A, row0 + 128, 1);
        PHASE_MID()
        MM(3)
        __builtin_amdgcn_s_setprio(0);
        asm volatile("s_waitcnt vmcnt(2)" ::: "memory");
        __builtin_amdgcn_s_barrier();
    }

    // drain garbage prefetch before LDS reuse / kernel end
    asm volatile("s_waitcnt vmcnt(0)" ::: "memory");
    __builtin_amdgcn_s_barrier();

    if (bx < 16) {
        // -------- RoPE epilogue (q / k) --------
        unsigned short* C = (bx < 8) ? q : k;
        const int hh = ((bx & 7) << 1) + bh;
#pragma unroll
        for (int mf = 0; mf < 8; ++mf)
#pragma unroll
            for (int nf = 0; nf < 2; ++nf) {
                int dh = wodd * 32 + nf * 16 + l15;
#pragma unroll
                for (int r = 0; r < 4; ++r) {
                    int rowg = row0 + wm * 128 + mf * 16 + quad * 4 + r;
                    int tt = rowg & 2047;
                    float c = cosT[tt * 64 + dh];
                    float s = sinT[tt * 64 + dh];
                    float x1 = acc[mf][nf][r];
                    float x2 = acc[mf][nf + 2][r];
                    size_t base = (size_t)rowg * DM_ + hh * D_ + dh;
                    C[base]         = f2bf(x1 * c - x2 * s);
                    C[base + HALF_] = f2bf(x1 * s + x2 * c);
                }
            }
    } else {
        // -------- V transpose epilogue: LDS [c][t] (256x256 bf16 = 128 KiB) --------
        // 4-short-chunk XOR swizzle: phys_tq = tq ^ ((c&15)<<2)  -> 2-way banks (free)
#pragma unroll
        for (int mf = 0; mf < 8; ++mf)
#pragma unroll
            for (int nf = 0; nf < 4; ++nf) {
                int c  = bh * 128 + wodd * 32 + (nf & 1) * 16 + (nf >> 1) * 64 + l15;
                int tq = wm * 32 + mf * 4 + quad;
                int phys = tq ^ ((c & 15) << 2);
                ushort4 o4;
                o4.x = f2bf(acc[mf][nf][0]); o4.y = f2bf(acc[mf][nf][1]);
                o4.z = f2bf(acc[mf][nf][2]); o4.w = f2bf(acc[mf][nf][3]);
                *(ushort4*)(sh + c * 256 + phys * 4) = o4;
            }
        __syncthreads();
        const int bb  = row0 >> 11;
        const int t0g = row0 & 2047;
        const int hb  = (bx - 16) << 1;
#pragma unroll
        for (int i = 0; i < 16; ++i) {
            int id = i * 512 + t;
            int c = id >> 5, chk = id & 31;
            int phys2 = (chk * 2) ^ ((c & 15) << 2);
            uint4 d = *(const uint4*)(sh + c * 256 + phys2 * 4);
            int h = hb + (c >> 7), dh = c & 127;
            *(uint4*)(vt + ((size_t)((bb * 16 + h) * 128 + dh)) * T_ + t0g + chk * 8) = d;
        }
    }
}

// ---------------- bf16 GEMM (fp32 out, BK=64): C[m,n] = sum_k A[m,k]*W[n,k] ----------
__global__ __launch_bounds__(256)
void gemm_bt(const unsigned short* __restrict__ A,
             const unsigned short* __restrict__ W,
             float* __restrict__ C, int M, int N, int K) {
    __shared__ unsigned short As[128 * 64];
    __shared__ unsigned short Bs[128 * 64];

    const int t    = threadIdx.x;
    const int lane = t & 63;
    const int w    = t >> 6;
    const int wm   = w >> 1, wn = w & 1;
    const int l15  = lane & 15, quad = lane >> 4;
    const int row0 = blockIdx.y * 128, col0 = blockIdx.x * 128;

    floatx4 acc[4][4];
    for (int i = 0; i < 4; ++i)
        for (int j = 0; j < 4; ++j)
            acc[i][j] = (floatx4){0.f, 0.f, 0.f, 0.f};

    const int nkt = K >> 6;
    for (int kt = 0; kt < nkt; ++kt) {
        if (kt) __syncthreads();
        for (int i = 0; i < 4; ++i) {
            int g  = i * 256 + t;
            int g0 = i * 256 + (t & ~63);
            int m  = g >> 3, c = g & 7;
            int k8 = c ^ (m & 7);
            gld16(A + (size_t)(row0 + m) * K + kt * 64 + k8 * 8,
                  (unsigned short*)As + (size_t)g0 * 8);
            gld16(W + (size_t)(col0 + m) * K + kt * 64 + k8 * 8,
                  (unsigned short*)Bs + (size_t)g0 * 8);
        }
        __syncthreads();

        for (int s = 0; s < 2; ++s) {
            short8 a[4], b[4];
            for (int mf = 0; mf < 4; ++mf) {
                int row = wm * 64 + mf * 16 + l15;
                int pc  = (quad + s * 4) ^ (row & 7);
                a[mf] = *(const short8*)(As + row * 64 + pc * 8);
            }
            for (int nf = 0; nf < 4; ++nf) {
                int row = wn * 64 + nf * 16 + l15;
                int pc  = (quad + s * 4) ^ (row & 7);
                b[nf] = *(const short8*)(Bs + row * 64 + pc * 8);
            }
            for (int mf = 0; mf < 4; ++mf)
                for (int nf = 0; nf < 4; ++nf)
                    acc[mf][nf] = __builtin_amdgcn_mfma_f32_16x16x32_bf16(
                        a[mf], b[nf], acc[mf][nf], 0, 0, 0);
        }
    }

    for (int mf = 0; mf < 4; ++mf)
        for (int nf = 0; nf < 4; ++nf)
            for (int r = 0; r < 4; ++r) {
                int row = row0 + wm * 64 + mf * 16 + quad * 4 + r;
                int col = col0 + wn * 64 + nf * 16 + l15;
                C[(size_t)row * N + col] = acc[mf][nf][r];
            }
}

// ---------------- causal flash attention, load-balanced (Br=64 pairs, Bc=64) ----------
__global__ __launch_bounds__(256)
void attn_kernel(const unsigned short* __restrict__ q,
                 const unsigned short* __restrict__ k,
                 const unsigned short* __restrict__ vt,
                 unsigned short* __restrict__ ao) {
    __shared__ unsigned short Ks[64 * 128];
    __shared__ unsigned short Vts[128 * 64];
    __shared__ unsigned short Pw[4][16 * 72];

    const int t    = threadIdx.x;
    const int lane = t & 63, w = t >> 6;
    const int l15  = lane & 15, quad = lane >> 4;
    const int j    = blockIdx.x;
    const int bh   = blockIdx.y;
    const int b    = bh >> 4, h = bh & 15;
    const int qt[2] = {31 - j, j};

    const size_t hoff  = (size_t)h * D_;
    const size_t bbase = (size_t)b * T_ * DM_;

    short8 qa[2][4];
    for (int rs = 0; rs < 2; ++rs) {
        const int qw = qt[rs] * 64 + w * 16;
        const unsigned short* qp = q + bbase + (size_t)(qw + l15) * DM_ + hoff + quad * 8;
        for (int ds = 0; ds < 4; ++ds)
            qa[rs][ds] = *(const short8*)(qp + ds * 32);
    }

    floatx4 o[2][8];
    floatx4 lacc[2];
    for (int rs = 0; rs < 2; ++rs) {
        for (int c = 0; c < 8; ++c) o[rs][c] = (floatx4){0.f, 0.f, 0.f, 0.f};
        lacc[rs] = (floatx4){0.f, 0.f, 0.f, 0.f};
    }
    const unsigned short one_bf = 0x3F80;
    short8 ones;
    for (int i = 0; i < 8; ++i) ones[i] = (short)one_bf;

    const float kS = 0.08838834764831845f;
    const int ktend = qt[0];

    for (int kt = 0; kt <= ktend; ++kt) {
        if (kt) __syncthreads();
        for (int i = 0; i < 4; ++i) {
            int it = w * 4 + i;
            int krow = it * 4 + (lane >> 4);
            int gck  = ((lane & 15) ^ (krow & 7));
            gld16(k + bbase + (size_t)(kt * 64 + krow) * DM_ + hoff + gck * 8,
                  (unsigned short*)Ks + it * 512);
            int vrow = it * 8 + (lane >> 3);
            int gcv  = ((lane & 7) ^ (vrow & 7));
            gld16(vt + ((size_t)bh * 128 + vrow) * T_ + kt * 64 + gcv * 8,
                  (unsigned short*)Vts + it * 512);
        }
        __syncthreads();

        for (int rs = 0; rs < 2; ++rs) {
            const int kd = qt[rs];
            if (kt > kd) continue;
            const int qw = qt[rs] * 64 + w * 16;

            floatx4 s[4];
            for (int f = 0; f < 4; ++f) s[f] = (floatx4){0.f, 0.f, 0.f, 0.f};
            for (int ds = 0; ds < 4; ++ds)
                for (int f = 0; f < 4; ++f) {
                    int krow = f * 16 + l15;
                    int phys = (ds * 4 + quad) ^ (krow & 7);
                    short8 bf = *(const short8*)(Ks + krow * 128 + phys * 8);
                    s[f] = __builtin_amdgcn_mfma_f32_16x16x32_bf16(qa[rs][ds], bf, s[f], 0, 0, 0);
                }

            const bool diag = (kt == kd);
            for (int r = 0; r < 4; ++r) {
                int qrow = qw + quad * 4 + r;
                for (int f = 0; f < 4; ++f) {
                    float x = s[f][r] * kS;
                    float e = __expf(x);
                    if (diag && (kt * 64 + f * 16 + l15 > qrow)) e = 0.f;
                    Pw[w][(quad * 4 + r) * 72 + f * 16 + l15] = f2bf(e);
                }
            }

            short8 pa0 = *(const short8*)(&Pw[w][l15 * 72 + quad * 8]);
            short8 pa1 = *(const short8*)(&Pw[w][l15 * 72 + 32 + quad * 8]);
            lacc[rs] = __builtin_amdgcn_mfma_f32_16x16x32_bf16(pa0, ones, lacc[rs], 0, 0, 0);
            lacc[rs] = __builtin_amdgcn_mfma_f32_16x16x32_bf16(pa1, ones, lacc[rs], 0, 0, 0);
            for (int c = 0; c < 8; ++c) {
                int vrow = c * 16 + l15;
                short8 b0 = *(const short8*)(Vts + vrow * 64 + ((quad) ^ (vrow & 7)) * 8);
                short8 b1 = *(const short8*)(Vts + vrow * 64 + ((4 + quad) ^ (vrow & 7)) * 8);
                o[rs][c] = __builtin_amdgcn_mfma_f32_16x16x32_bf16(pa0, b0, o[rs][c], 0, 0, 0);
                o[rs][c] = __builtin_amdgcn_mfma_f32_16x16x32_bf16(pa1, b1, o[rs][c], 0, 0, 0);
            }
        }
    }

    for (int rs = 0; rs < 2; ++rs) {
        const int qw = qt[rs] * 64 + w * 16;
        for (int r = 0; r < 4; ++r) {
            float inv = 1.0f / lacc[rs][r];
            int qrow = qw + quad * 4 + r;
            size_t obase = bbase + (size_t)qrow * DM_ + hoff;
            for (int c = 0; c < 8; ++c)
                ao[obase + c * 16 + l15] = f2bf(o[rs][c][r] * inv);
        }
    }
}

extern "C" void kernel_launch(void* const* d_in, const int* in_sizes, int n_in,
                              void* d_out, int out_size, void* d_ws, size_t ws_size,
                              hipStream_t stream) {
    const float* x    = (const float*)d_in[0];
    const float* wq   = (const float*)d_in[1];
    const float* wk   = (const float*)d_in[2];
    const float* wv   = (const float*)d_in[3];
    const float* wo   = (const float*)d_in[4];
    const float* cosT = (const float*)d_in[5];
    const float* sinT = (const float*)d_in[6];
    float* out = (float*)d_out;

    const size_t NX = (size_t)B_ * T_ * DM_;
    const size_t NW = (size_t)DM_ * DM_;

    unsigned short* xb  = (unsigned short*)d_ws;
    unsigned short* wqb = xb + NX;
    unsigned short* wob = wqb + 3 * NW;
    unsigned short* qb  = wob + NW;
    unsigned short* kb  = qb + NX;
    unsigned short* vtb = kb + NX;
    unsigned short* aob = vtb + NX;

    conv_all<<<dim3((int)(NW / 4 / 256), 6), 256, 0, stream>>>(
        x, wq, wk, wv, wo, xb, wqb, (int)(NW / 4));

    gemm_qkv<<<dim3(24, 16), 512, 0, stream>>>(xb, wqb, qb, kb, vtb, cosT, sinT);

    attn_kernel<<<dim3(16, B_ * H_), 256, 0, stream>>>(qb, kb, vtb, aob);

    gemm_bt<<<dim3(16, 32), 256, 0, stream>>>(aob, wob, out, B_ * T_, DM_, DM_);
}

// Round 2
// 371.875 us; speedup vs baseline: 1.0083x; 1.0083x over previous
//
#include <hip/hip_runtime.h>

typedef __attribute__((ext_vector_type(8))) short short8;
typedef __attribute__((ext_vector_type(4))) float floatx4;

#define B_ 2
#define T_ 2048
#define DM_ 2048
#define H_ 16
#define D_ 128
#define HALF_ 64

__device__ inline unsigned short f2bf(float f) {
    union { float f; unsigned u; } v; v.f = f;
    unsigned r = (v.u + 0x7fffu + ((v.u >> 16) & 1u)) >> 16;
    return (unsigned short)r;
}

__device__ inline void gld16(const void* g, void* l) {
    __builtin_amdgcn_global_load_lds(
        (__attribute__((address_space(1))) void*)g,
        (__attribute__((address_space(3))) void*)l,
        16, 0, 0);
}

// ---------------- fused fp32 -> bf16 convert: x (2 slices) + 4 weights ----------------
__global__ void conv_all(const float* __restrict__ x,
                         const float* __restrict__ w0, const float* __restrict__ w1,
                         const float* __restrict__ w2, const float* __restrict__ w3,
                         unsigned short* __restrict__ xb,
                         unsigned short* __restrict__ wb, int n4w) {
    int y = blockIdx.y;
    int i = blockIdx.x * 256 + threadIdx.x;
    const float* src;
    ushort4* dst;
    if (y < 2) { src = x + (size_t)y * n4w * 4; dst = (ushort4*)xb + (size_t)y * n4w; }
    else {
        src = (y == 2) ? w0 : (y == 3) ? w1 : (y == 4) ? w2 : w3;
        dst = (ushort4*)wb + (size_t)(y - 2) * n4w;
    }
    float4 f = ((const float4*)src)[i];
    ushort4 o;
    o.x = f2bf(f.x); o.y = f2bf(f.y); o.z = f2bf(f.z); o.w = f2bf(f.w);
    dst[i] = o;
}

// ---------------- fused QKV GEMM + RoPE + V-transpose: 128x256 tile, 2-phase/K-tile --
// grid (24, 32) = 768 blocks -> exactly 3 rounds on 256 CUs (no tail).
// 512 threads = 8 waves (2M x 4N), per-wave 64x64 output, acc[4][4].
// LDS 96 KiB: A dbuf 2x(128x64) at 0, B dbuf 2x(256x64) at +16384 shorts.
// 16B-chunk XOR swizzle phys = logical ^ (row&7), applied on the pre-swizzled global
// source (LDS dest stays linear for global_load_lds).
// Per K-tile: phase s=0 {stage 6 chunks of t+1; 8 ds_read; bar; lgkm0; 16 MFMA; bar},
//             phase s=1 {8 ds_read; bar; lgkm0; 16 MFMA; vmcnt(0); bar}.
// Single end-of-tile drain: loads have ~2 compute phases of lead, so the drain is ~free.
// Per-wave cols are non-contiguous within head: {o..o+32} U {o+64..o+96} so the RoPE
// pair (dh, dh+64) is acc[mf][nf] / acc[mf][nf+2] in-register.

__global__ __launch_bounds__(512, 2)
void gemm_qkv(const unsigned short* __restrict__ A,
              const unsigned short* __restrict__ W,
              unsigned short* __restrict__ q,
              unsigned short* __restrict__ k,
              unsigned short* __restrict__ vt,
              const float* __restrict__ cosT,
              const float* __restrict__ sinT) {
    __shared__ unsigned short sh[49152];   // 96 KiB

    const int t    = threadIdx.x;          // 0..511
    const int lane = t & 63;
    const int w    = t >> 6;               // 0..7
    const int wm   = w >> 2;               // 0..1  (M half: 64 rows)
    const int wn   = w & 3;                // 0..3  (col group)
    const int l15  = lane & 15, quad = lane >> 4;
    const int bx   = blockIdx.x;           // 0..23
    const int row0 = blockIdx.y * 128;
    const int col0 = bx * 256;
    const int K    = DM_;
    // column-row base in B-tile for this wave (non-contiguous RoPE-friendly mapping)
    const int browbase = (wn >> 1) * 128 + (wn & 1) * 32;

    floatx4 acc[4][4];
#pragma unroll
    for (int i = 0; i < 4; ++i)
#pragma unroll
        for (int j = 0; j < 4; ++j)
            acc[i][j] = (floatx4){0.f, 0.f, 0.f, 0.f};

    // one STG stages 64 rows (512 thr x 16B = 8KB); grow = global row base of chunk,
    // dst = LDS short-offset of chunk base. Global source col pre-swizzled; LDS linear.
#define STG(dst, srcp, grow)                                                  \
    { int m_ = t >> 3; int k8_ = (t & 7) ^ (m_ & 7);                          \
      gld16((srcp) + (size_t)((grow) + m_) * K + ktn * 64 + k8_ * 8,          \
            sh + (dst) + (t & ~63) * 8); }

#define STAGE_TILE(nb)                                                        \
    { STG(16384 + (nb) * 16384,         W, col0);                             \
      STG(16384 + (nb) * 16384 + 4096,  W, col0 + 64);                        \
      STG(16384 + (nb) * 16384 + 8192,  W, col0 + 128);                       \
      STG(16384 + (nb) * 16384 + 12288, W, col0 + 192);                       \
      STG((nb) * 8192,                  A, row0);                             \
      STG((nb) * 8192 + 4096,           A, row0 + 64); }

#define READ_FRAGS(S)                                                         \
    { _Pragma("unroll") for (int mf = 0; mf < 4; ++mf) {                      \
        int row_ = wm * 64 + mf * 16 + l15;                                   \
        int pc_  = (quad + (S) * 4) ^ (row_ & 7);                             \
        a[mf] = *(const short8*)(sh + aoff + row_ * 64 + pc_ * 8); }          \
      _Pragma("unroll") for (int nf = 0; nf < 4; ++nf) {                      \
        int row_ = browbase + (nf & 1) * 16 + (nf >> 1) * 64 + l15;           \
        int pc_  = (quad + (S) * 4) ^ (row_ & 7);                             \
        b[nf] = *(const short8*)(sh + boff + row_ * 64 + pc_ * 8); } }

#define MFMA16()                                                              \
    { _Pragma("unroll") for (int mf = 0; mf < 4; ++mf)                        \
      _Pragma("unroll") for (int nf = 0; nf < 4; ++nf)                        \
        acc[mf][nf] = __builtin_amdgcn_mfma_f32_16x16x32_bf16(                \
            a[mf], b[nf], acc[mf][nf], 0, 0, 0); }

    // ---- prologue: stage K-tile 0 into buf0
    {
        const int ktn = 0;
        STAGE_TILE(0)
    }
    asm volatile("s_waitcnt vmcnt(0)" ::: "memory");
    __builtin_amdgcn_s_barrier();

    for (int kt = 0; kt < 32; ++kt) {
        const int cb   = kt & 1, nb = cb ^ 1;
        const int ktn  = kt + 1;
        const int aoff = cb * 8192;
        const int boff = 16384 + cb * 16384;
        short8 a[4], b[4];

        // ---- phase 0 (k-cols 0..31): stage next tile early, then read + MFMA
        if (kt < 31) { STAGE_TILE(nb) }
        READ_FRAGS(0)
        __builtin_amdgcn_s_barrier();
        asm volatile("s_waitcnt lgkmcnt(0)" ::: "memory");
        __builtin_amdgcn_sched_barrier(0);
        __builtin_amdgcn_s_setprio(1);
        MFMA16()
        __builtin_amdgcn_s_setprio(0);
        __builtin_amdgcn_s_barrier();

        // ---- phase 1 (k-cols 32..63): read + MFMA, then single counted drain
        READ_FRAGS(1)
        __builtin_amdgcn_s_barrier();
        asm volatile("s_waitcnt lgkmcnt(0)" ::: "memory");
        __builtin_amdgcn_sched_barrier(0);
        __builtin_amdgcn_s_setprio(1);
        MFMA16()
        __builtin_amdgcn_s_setprio(0);
        asm volatile("s_waitcnt vmcnt(0)" ::: "memory");  // next tile's 6 chunks: issued
        __builtin_amdgcn_s_barrier();                     // ~2 phases ago -> near-free
    }

    if (bx < 16) {
        // -------- RoPE epilogue (q / k) --------
        unsigned short* C = (bx < 8) ? q : k;
        const int hh = ((bx & 7) << 1) + (wn >> 1);
#pragma unroll
        for (int mf = 0; mf < 4; ++mf)
#pragma unroll
            for (int nf = 0; nf < 2; ++nf) {
                int dh = (wn & 1) * 32 + nf * 16 + l15;
#pragma unroll
                for (int r = 0; r < 4; ++r) {
                    int rowg = row0 + wm * 64 + mf * 16 + quad * 4 + r;
                    int tt = rowg & 2047;
                    float c = cosT[tt * 64 + dh];
                    float s = sinT[tt * 64 + dh];
                    float x1 = acc[mf][nf][r];
                    float x2 = acc[mf][nf + 2][r];
                    size_t base = (size_t)rowg * DM_ + hh * D_ + dh;
                    C[base]         = f2bf(x1 * c - x2 * s);
                    C[base + HALF_] = f2bf(x1 * s + x2 * c);
                }
            }
    } else {
        // -------- V transpose epilogue: LDS [256 c][128 t] bf16 = 64 KiB --------
        // XOR swizzle at 8-short t-chunk granularity: phys_tc = tc ^ (c&15) -> ~2-way
#pragma unroll
        for (int mf = 0; mf < 4; ++mf)
#pragma unroll
            for (int nf = 0; nf < 4; ++nf) {
                int c  = browbase + (nf & 1) * 16 + (nf >> 1) * 64 + l15;
                int tq = wm * 16 + mf * 4 + quad;        // t = tq*4 + r
                int tc = tq >> 1, sub = tq & 1;
                int ptc = tc ^ (c & 15);
                ushort4 o4;
                o4.x = f2bf(acc[mf][nf][0]); o4.y = f2bf(acc[mf][nf][1]);
                o4.z = f2bf(acc[mf][nf][2]); o4.w = f2bf(acc[mf][nf][3]);
                *(ushort4*)(sh + c * 128 + ptc * 8 + sub * 4) = o4;
            }
        __syncthreads();
        const int bb  = row0 >> 11;
        const int t0g = row0 & 2047;
        const int hb  = (bx - 16) << 1;
#pragma unroll
        for (int i = 0; i < 8; ++i) {
            int id = i * 512 + t;
            int c = id >> 4, tc = id & 15;
            int ptc = tc ^ (c & 15);
            uint4 d = *(const uint4*)(sh + c * 128 + ptc * 8);
            int h = hb + (c >> 7), dh = c & 127;
            *(uint4*)(vt + ((size_t)((bb * 16 + h) * 128 + dh)) * T_ + t0g + tc * 8) = d;
        }
    }
#undef STG
#undef STAGE_TILE
#undef READ_FRAGS
#undef MFMA16
}

// ---------------- bf16 GEMM (fp32 out, BK=64): C[m,n] = sum_k A[m,k]*W[n,k] ----------
__global__ __launch_bounds__(256)
void gemm_bt(const unsigned short* __restrict__ A,
             const unsigned short* __restrict__ W,
             float* __restrict__ C, int M, int N, int K) {
    __shared__ unsigned short As[128 * 64];
    __shared__ unsigned short Bs[128 * 64];

    const int t    = threadIdx.x;
    const int lane = t & 63;
    const int w    = t >> 6;
    const int wm   = w >> 1, wn = w & 1;
    const int l15  = lane & 15, quad = lane >> 4;
    const int row0 = blockIdx.y * 128, col0 = blockIdx.x * 128;

    floatx4 acc[4][4];
    for (int i = 0; i < 4; ++i)
        for (int j = 0; j < 4; ++j)
            acc[i][j] = (floatx4){0.f, 0.f, 0.f, 0.f};

    const int nkt = K >> 6;
    for (int kt = 0; kt < nkt; ++kt) {
        if (kt) __syncthreads();
        for (int i = 0; i < 4; ++i) {
            int g  = i * 256 + t;
            int g0 = i * 256 + (t & ~63);
            int m  = g >> 3, c = g & 7;
            int k8 = c ^ (m & 7);
            gld16(A + (size_t)(row0 + m) * K + kt * 64 + k8 * 8,
                  (unsigned short*)As + (size_t)g0 * 8);
            gld16(W + (size_t)(col0 + m) * K + kt * 64 + k8 * 8,
                  (unsigned short*)Bs + (size_t)g0 * 8);
        }
        __syncthreads();

        for (int s = 0; s < 2; ++s) {
            short8 a[4], b[4];
            for (int mf = 0; mf < 4; ++mf) {
                int row = wm * 64 + mf * 16 + l15;
                int pc  = (quad + s * 4) ^ (row & 7);
                a[mf] = *(const short8*)(As + row * 64 + pc * 8);
            }
            for (int nf = 0; nf < 4; ++nf) {
                int row = wn * 64 + nf * 16 + l15;
                int pc  = (quad + s * 4) ^ (row & 7);
                b[nf] = *(const short8*)(Bs + row * 64 + pc * 8);
            }
            for (int mf = 0; mf < 4; ++mf)
                for (int nf = 0; nf < 4; ++nf)
                    acc[mf][nf] = __builtin_amdgcn_mfma_f32_16x16x32_bf16(
                        a[mf], b[nf], acc[mf][nf], 0, 0, 0);
        }
    }

    for (int mf = 0; mf < 4; ++mf)
        for (int nf = 0; nf < 4; ++nf)
            for (int r = 0; r < 4; ++r) {
                int row = row0 + wm * 64 + mf * 16 + quad * 4 + r;
                int col = col0 + wn * 64 + nf * 16 + l15;
                C[(size_t)row * N + col] = acc[mf][nf][r];
            }
}

// ---------------- causal flash attention, load-balanced (Br=64 pairs, Bc=64) ----------
__global__ __launch_bounds__(256)
void attn_kernel(const unsigned short* __restrict__ q,
                 const unsigned short* __restrict__ k,
                 const unsigned short* __restrict__ vt,
                 unsigned short* __restrict__ ao) {
    __shared__ unsigned short Ks[64 * 128];
    __shared__ unsigned short Vts[128 * 64];
    __shared__ unsigned short Pw[4][16 * 72];

    const int t    = threadIdx.x;
    const int lane = t & 63, w = t >> 6;
    const int l15  = lane & 15, quad = lane >> 4;
    const int j    = blockIdx.x;
    const int bh   = blockIdx.y;
    const int b    = bh >> 4, h = bh & 15;
    const int qt[2] = {31 - j, j};

    const size_t hoff  = (size_t)h * D_;
    const size_t bbase = (size_t)b * T_ * DM_;

    short8 qa[2][4];
    for (int rs = 0; rs < 2; ++rs) {
        const int qw = qt[rs] * 64 + w * 16;
        const unsigned short* qp = q + bbase + (size_t)(qw + l15) * DM_ + hoff + quad * 8;
        for (int ds = 0; ds < 4; ++ds)
            qa[rs][ds] = *(const short8*)(qp + ds * 32);
    }

    floatx4 o[2][8];
    floatx4 lacc[2];
    for (int rs = 0; rs < 2; ++rs) {
        for (int c = 0; c < 8; ++c) o[rs][c] = (floatx4){0.f, 0.f, 0.f, 0.f};
        lacc[rs] = (floatx4){0.f, 0.f, 0.f, 0.f};
    }
    const unsigned short one_bf = 0x3F80;
    short8 ones;
    for (int i = 0; i < 8; ++i) ones[i] = (short)one_bf;

    const float kS = 0.08838834764831845f;
    const int ktend = qt[0];

    for (int kt = 0; kt <= ktend; ++kt) {
        if (kt) __syncthreads();
        for (int i = 0; i < 4; ++i) {
            int it = w * 4 + i;
            int krow = it * 4 + (lane >> 4);
            int gck  = ((lane & 15) ^ (krow & 7));
            gld16(k + bbase + (size_t)(kt * 64 + krow) * DM_ + hoff + gck * 8,
                  (unsigned short*)Ks + it * 512);
            int vrow = it * 8 + (lane >> 3);
            int gcv  = ((lane & 7) ^ (vrow & 7));
            gld16(vt + ((size_t)bh * 128 + vrow) * T_ + kt * 64 + gcv * 8,
                  (unsigned short*)Vts + it * 512);
        }
        __syncthreads();

        for (int rs = 0; rs < 2; ++rs) {
            const int kd = qt[rs];
            if (kt > kd) continue;
            const int qw = qt[rs] * 64 + w * 16;

            floatx4 s[4];
            for (int f = 0; f < 4; ++f) s[f] = (floatx4){0.f, 0.f, 0.f, 0.f};
            for (int ds = 0; ds < 4; ++ds)
                for (int f = 0; f < 4; ++f) {
                    int krow = f * 16 + l15;
                    int phys = (ds * 4 + quad) ^ (krow & 7);
                    short8 bf = *(const short8*)(Ks + krow * 128 + phys * 8);
                    s[f] = __builtin_amdgcn_mfma_f32_16x16x32_bf16(qa[rs][ds], bf, s[f], 0, 0, 0);
                }

            const bool diag = (kt == kd);
            for (int r = 0; r < 4; ++r) {
                int qrow = qw + quad * 4 + r;
                for (int f = 0; f < 4; ++f) {
                    float x = s[f][r] * kS;
                    float e = __expf(x);
                    if (diag && (kt * 64 + f * 16 + l15 > qrow)) e = 0.f;
                    Pw[w][(quad * 4 + r) * 72 + f * 16 + l15] = f2bf(e);
                }
            }

            short8 pa0 = *(const short8*)(&Pw[w][l15 * 72 + quad * 8]);
            short8 pa1 = *(const short8*)(&Pw[w][l15 * 72 + 32 + quad * 8]);
            lacc[rs] = __builtin_amdgcn_mfma_f32_16x16x32_bf16(pa0, ones, lacc[rs], 0, 0, 0);
            lacc[rs] = __builtin_amdgcn_mfma_f32_16x16x32_bf16(pa1, ones, lacc[rs], 0, 0, 0);
            for (int c = 0; c < 8; ++c) {
                int vrow = c * 16 + l15;
                short8 b0 = *(const short8*)(Vts + vrow * 64 + ((quad) ^ (vrow & 7)) * 8);
                short8 b1 = *(const short8*)(Vts + vrow * 64 + ((4 + quad) ^ (vrow & 7)) * 8);
                o[rs][c] = __builtin_amdgcn_mfma_f32_16x16x32_bf16(pa0, b0, o[rs][c], 0, 0, 0);
                o[rs][c] = __builtin_amdgcn_mfma_f32_16x16x32_bf16(pa1, b1, o[rs][c], 0, 0, 0);
            }
        }
    }

    for (int rs = 0; rs < 2; ++rs) {
        const int qw = qt[rs] * 64 + w * 16;
        for (int r = 0; r < 4; ++r) {
            float inv = 1.0f / lacc[rs][r];
            int qrow = qw + quad * 4 + r;
            size_t obase = bbase + (size_t)qrow * DM_ + hoff;
            for (int c = 0; c < 8; ++c)
                ao[obase + c * 16 + l15] = f2bf(o[rs][c][r] * inv);
        }
    }
}

extern "C" void kernel_launch(void* const* d_in, const int* in_sizes, int n_in,
                              void* d_out, int out_size, void* d_ws, size_t ws_size,
                              hipStream_t stream) {
    const float* x    = (const float*)d_in[0];
    const float* wq   = (const float*)d_in[1];
    const float* wk   = (const float*)d_in[2];
    const float* wv   = (const float*)d_in[3];
    const float* wo   = (const float*)d_in[4];
    const float* cosT = (const float*)d_in[5];
    const float* sinT = (const float*)d_in[6];
    float* out = (float*)d_out;

    const size_t NX = (size_t)B_ * T_ * DM_;
    const size_t NW = (size_t)DM_ * DM_;

    unsigned short* xb  = (unsigned short*)d_ws;
    unsigned short* wqb = xb + NX;
    unsigned short* wob = wqb + 3 * NW;
    unsigned short* qb  = wob + NW;
    unsigned short* kb  = qb + NX;
    unsigned short* vtb = kb + NX;
    unsigned short* aob = vtb + NX;

    conv_all<<<dim3((int)(NW / 4 / 256), 6), 256, 0, stream>>>(
        x, wq, wk, wv, wo, xb, wqb, (int)(NW / 4));

    gemm_qkv<<<dim3(24, 32), 512, 0, stream>>>(xb, wqb, qb, kb, vtb, cosT, sinT);

    attn_kernel<<<dim3(16, B_ * H_), 256, 0, stream>>>(qb, kb, vtb, aob);

    gemm_bt<<<dim3(16, 32), 256, 0, stream>>>(aob, wob, out, B_ * T_, DM_, DM_);
}

// Round 3
// 367.795 us; speedup vs baseline: 1.0195x; 1.0111x over previous
//
#include <hip/hip_runtime.h>

typedef __attribute__((ext_vector_type(8))) short short8;
typedef __attribute__((ext_vector_type(4))) float floatx4;

#define B_ 2
#define T_ 2048
#define DM_ 2048
#define H_ 16
#define D_ 128
#define HALF_ 64

__device__ inline unsigned short f2bf(float f) {
    union { float f; unsigned u; } v; v.f = f;
    unsigned r = (v.u + 0x7fffu + ((v.u >> 16) & 1u)) >> 16;
    return (unsigned short)r;
}

__device__ inline void gld16(const void* g, void* l) {
    __builtin_amdgcn_global_load_lds(
        (__attribute__((address_space(1))) void*)g,
        (__attribute__((address_space(3))) void*)l,
        16, 0, 0);
}

// ---------------- fused fp32 -> bf16 convert: x (2 slices) + 4 weights ----------------
__global__ void conv_all(const float* __restrict__ x,
                         const float* __restrict__ w0, const float* __restrict__ w1,
                         const float* __restrict__ w2, const float* __restrict__ w3,
                         unsigned short* __restrict__ xb,
                         unsigned short* __restrict__ wb, int n4w) {
    int y = blockIdx.y;
    int i = blockIdx.x * 256 + threadIdx.x;
    const float* src;
    ushort4* dst;
    if (y < 2) { src = x + (size_t)y * n4w * 4; dst = (ushort4*)xb + (size_t)y * n4w; }
    else {
        src = (y == 2) ? w0 : (y == 3) ? w1 : (y == 4) ? w2 : w3;
        dst = (ushort4*)wb + (size_t)(y - 2) * n4w;
    }
    float4 f = ((const float4*)src)[i];
    ushort4 o;
    o.x = f2bf(f.x); o.y = f2bf(f.y); o.z = f2bf(f.z); o.w = f2bf(f.w);
    dst[i] = o;
}

// ---------------- fused QKV GEMM + RoPE + V-transpose: 128x256 tile, 2-phase/K-tile --
// grid (24, 32) = 768 blocks -> exactly 3 rounds on 256 CUs (no tail).
// 512 threads = 8 waves (2M x 4N), per-wave 64x64 output, acc[4][4].
// LDS 144 KiB TRIPLE buffer: A 3x(128x64) at 0, B 3x(256x64) at +24576 shorts.
// Pipeline depth 2: during tile kt we stage tile kt+2; end-of-tile gate is vmcnt(6)
// (leaves kt+2's 6 loads in flight, requires kt+1's - issued a full tile earlier -
// to have retired). vmcnt(0) only for the last two tiles. This is the m201 principle:
// counted gates only work when in-flight depth > 1 tile.
// 16B-chunk XOR swizzle phys = logical ^ (row&7) on the pre-swizzled global source.
// Per-wave cols are non-contiguous within head: {o..o+32} U {o+64..o+96} so the RoPE
// pair (dh, dh+64) is acc[mf][nf] / acc[mf][nf+2] in-register.

__global__ __launch_bounds__(512, 2)
void gemm_qkv(const unsigned short* __restrict__ A,
              const unsigned short* __restrict__ W,
              unsigned short* __restrict__ q,
              unsigned short* __restrict__ k,
              unsigned short* __restrict__ vt,
              const float* __restrict__ cosT,
              const float* __restrict__ sinT) {
    __shared__ unsigned short sh[73728];   // 144 KiB

    const int t    = threadIdx.x;          // 0..511
    const int lane = t & 63;
    const int w    = t >> 6;               // 0..7
    const int wm   = w >> 2;               // 0..1  (M half: 64 rows)
    const int wn   = w & 3;                // 0..3  (col group)
    const int l15  = lane & 15, quad = lane >> 4;
    const int bx   = blockIdx.x;           // 0..23
    const int row0 = blockIdx.y * 128;
    const int col0 = bx * 256;
    const int K    = DM_;
    // column-row base in B-tile for this wave (non-contiguous RoPE-friendly mapping)
    const int browbase = (wn >> 1) * 128 + (wn & 1) * 32;

    floatx4 acc[4][4];
#pragma unroll
    for (int i = 0; i < 4; ++i)
#pragma unroll
        for (int j = 0; j < 4; ++j)
            acc[i][j] = (floatx4){0.f, 0.f, 0.f, 0.f};

    // one STG stages 64 rows (512 thr x 16B = 8KB); grow = global row base of chunk,
    // dst = LDS short-offset of chunk base. Global source col pre-swizzled; LDS linear.
#define STG(dst, srcp, grow)                                                  \
    { int m_ = t >> 3; int k8_ = (t & 7) ^ (m_ & 7);                          \
      gld16((srcp) + (size_t)((grow) + m_) * K + ktn * 64 + k8_ * 8,          \
            sh + (dst) + (t & ~63) * 8); }

#define STAGE_TILE(nb)                                                        \
    { STG(24576 + (nb) * 16384,         W, col0);                             \
      STG(24576 + (nb) * 16384 + 4096,  W, col0 + 64);                        \
      STG(24576 + (nb) * 16384 + 8192,  W, col0 + 128);                       \
      STG(24576 + (nb) * 16384 + 12288, W, col0 + 192);                       \
      STG((nb) * 8192,                  A, row0);                             \
      STG((nb) * 8192 + 4096,           A, row0 + 64); }

#define READ_FRAGS(S)                                                         \
    { _Pragma("unroll") for (int mf = 0; mf < 4; ++mf) {                      \
        int row_ = wm * 64 + mf * 16 + l15;                                   \
        int pc_  = (quad + (S) * 4) ^ (row_ & 7);                             \
        a[mf] = *(const short8*)(sh + aoff + row_ * 64 + pc_ * 8); }          \
      _Pragma("unroll") for (int nf = 0; nf < 4; ++nf) {                      \
        int row_ = browbase + (nf & 1) * 16 + (nf >> 1) * 64 + l15;           \
        int pc_  = (quad + (S) * 4) ^ (row_ & 7);                             \
        b[nf] = *(const short8*)(sh + boff + row_ * 64 + pc_ * 8); } }

#define MFMA16()                                                              \
    { _Pragma("unroll") for (int mf = 0; mf < 4; ++mf)                        \
      _Pragma("unroll") for (int nf = 0; nf < 4; ++nf)                        \
        acc[mf][nf] = __builtin_amdgcn_mfma_f32_16x16x32_bf16(                \
            a[mf], b[nf], acc[mf][nf], 0, 0, 0); }

    // ---- prologue: stage K-tile 0 -> buf0, K-tile 1 -> buf1 (depth 2)
    { const int ktn = 0; STAGE_TILE(0) }
    { const int ktn = 1; STAGE_TILE(1) }
    asm volatile("s_waitcnt vmcnt(6)" ::: "memory");   // tile0 retired; tile1 may fly
    __builtin_amdgcn_s_barrier();

    int cur = 0;                                       // kt % 3
    for (int kt = 0; kt < 32; ++kt) {
        const int sb   = (cur >= 1) ? cur - 1 : 2;     // (kt+2) % 3
        const int ktn  = kt + 2;
        const int aoff = cur * 8192;
        const int boff = 24576 + cur * 16384;
        short8 a[4], b[4];

        // ---- phase 0 (k-cols 0..31): stage tile kt+2 early, then read + MFMA
        if (kt < 30) { STAGE_TILE(sb) }
        READ_FRAGS(0)
        __builtin_amdgcn_s_barrier();
        asm volatile("s_waitcnt lgkmcnt(0)" ::: "memory");
        __builtin_amdgcn_sched_barrier(0);
        __builtin_amdgcn_s_setprio(1);
        MFMA16()
        __builtin_amdgcn_s_setprio(0);
        __builtin_amdgcn_s_barrier();

        // ---- phase 1 (k-cols 32..63): read + MFMA, counted end-of-tile gate
        READ_FRAGS(1)
        __builtin_amdgcn_s_barrier();
        asm volatile("s_waitcnt lgkmcnt(0)" ::: "memory");
        __builtin_amdgcn_sched_barrier(0);
        __builtin_amdgcn_s_setprio(1);
        MFMA16()
        __builtin_amdgcn_s_setprio(0);
        if (kt < 30) asm volatile("s_waitcnt vmcnt(6)" ::: "memory");
        else         asm volatile("s_waitcnt vmcnt(0)" ::: "memory");
        __builtin_amdgcn_s_barrier();
        cur = (cur + 1 == 3) ? 0 : cur + 1;
    }

    if (bx < 16) {
        // -------- RoPE epilogue (q / k) --------
        unsigned short* C = (bx < 8) ? q : k;
        const int hh = ((bx & 7) << 1) + (wn >> 1);
#pragma unroll
        for (int mf = 0; mf < 4; ++mf)
#pragma unroll
            for (int nf = 0; nf < 2; ++nf) {
                int dh = (wn & 1) * 32 + nf * 16 + l15;
#pragma unroll
                for (int r = 0; r < 4; ++r) {
                    int rowg = row0 + wm * 64 + mf * 16 + quad * 4 + r;
                    int tt = rowg & 2047;
                    float c = cosT[tt * 64 + dh];
                    float s = sinT[tt * 64 + dh];
                    float x1 = acc[mf][nf][r];
                    float x2 = acc[mf][nf + 2][r];
                    size_t base = (size_t)rowg * DM_ + hh * D_ + dh;
                    C[base]         = f2bf(x1 * c - x2 * s);
                    C[base + HALF_] = f2bf(x1 * s + x2 * c);
                }
            }
    } else {
        // -------- V transpose epilogue: LDS [256 c][128 t] bf16 = 64 KiB --------
        // XOR swizzle at 8-short t-chunk granularity: phys_tc = tc ^ (c&15) -> ~2-way
#pragma unroll
        for (int mf = 0; mf < 4; ++mf)
#pragma unroll
            for (int nf = 0; nf < 4; ++nf) {
                int c  = browbase + (nf & 1) * 16 + (nf >> 1) * 64 + l15;
                int tq = wm * 16 + mf * 4 + quad;        // t = tq*4 + r
                int tc = tq >> 1, sub = tq & 1;
                int ptc = tc ^ (c & 15);
                ushort4 o4;
                o4.x = f2bf(acc[mf][nf][0]); o4.y = f2bf(acc[mf][nf][1]);
                o4.z = f2bf(acc[mf][nf][2]); o4.w = f2bf(acc[mf][nf][3]);
                *(ushort4*)(sh + c * 128 + ptc * 8 + sub * 4) = o4;
            }
        __syncthreads();
        const int bb  = row0 >> 11;
        const int t0g = row0 & 2047;
        const int hb  = (bx - 16) << 1;
#pragma unroll
        for (int i = 0; i < 8; ++i) {
            int id = i * 512 + t;
            int c = id >> 4, tc = id & 15;
            int ptc = tc ^ (c & 15);
            uint4 d = *(const uint4*)(sh + c * 128 + ptc * 8);
            int h = hb + (c >> 7), dh = c & 127;
            *(uint4*)(vt + ((size_t)((bb * 16 + h) * 128 + dh)) * T_ + t0g + tc * 8) = d;
        }
    }
#undef STG
#undef STAGE_TILE
#undef READ_FRAGS
#undef MFMA16
}

// ---------------- bf16 GEMM (fp32 out, BK=64): C[m,n] = sum_k A[m,k]*W[n,k] ----------
__global__ __launch_bounds__(256)
void gemm_bt(const unsigned short* __restrict__ A,
             const unsigned short* __restrict__ W,
             float* __restrict__ C, int M, int N, int K) {
    __shared__ unsigned short As[128 * 64];
    __shared__ unsigned short Bs[128 * 64];

    const int t    = threadIdx.x;
    const int lane = t & 63;
    const int w    = t >> 6;
    const int wm   = w >> 1, wn = w & 1;
    const int l15  = lane & 15, quad = lane >> 4;
    const int row0 = blockIdx.y * 128, col0 = blockIdx.x * 128;

    floatx4 acc[4][4];
    for (int i = 0; i < 4; ++i)
        for (int j = 0; j < 4; ++j)
            acc[i][j] = (floatx4){0.f, 0.f, 0.f, 0.f};

    const int nkt = K >> 6;
    for (int kt = 0; kt < nkt; ++kt) {
        if (kt) __syncthreads();
        for (int i = 0; i < 4; ++i) {
            int g  = i * 256 + t;
            int g0 = i * 256 + (t & ~63);
            int m  = g >> 3, c = g & 7;
            int k8 = c ^ (m & 7);
            gld16(A + (size_t)(row0 + m) * K + kt * 64 + k8 * 8,
                  (unsigned short*)As + (size_t)g0 * 8);
            gld16(W + (size_t)(col0 + m) * K + kt * 64 + k8 * 8,
                  (unsigned short*)Bs + (size_t)g0 * 8);
        }
        __syncthreads();

        for (int s = 0; s < 2; ++s) {
            short8 a[4], b[4];
            for (int mf = 0; mf < 4; ++mf) {
                int row = wm * 64 + mf * 16 + l15;
                int pc  = (quad + s * 4) ^ (row & 7);
                a[mf] = *(const short8*)(As + row * 64 + pc * 8);
            }
            for (int nf = 0; nf < 4; ++nf) {
                int row = wn * 64 + nf * 16 + l15;
                int pc  = (quad + s * 4) ^ (row & 7);
                b[nf] = *(const short8*)(Bs + row * 64 + pc * 8);
            }
            for (int mf = 0; mf < 4; ++mf)
                for (int nf = 0; nf < 4; ++nf)
                    acc[mf][nf] = __builtin_amdgcn_mfma_f32_16x16x32_bf16(
                        a[mf], b[nf], acc[mf][nf], 0, 0, 0);
        }
    }

    for (int mf = 0; mf < 4; ++mf)
        for (int nf = 0; nf < 4; ++nf)
            for (int r = 0; r < 4; ++r) {
                int row = row0 + wm * 64 + mf * 16 + quad * 4 + r;
                int col = col0 + wn * 64 + nf * 16 + l15;
                C[(size_t)row * N + col] = acc[mf][nf][r];
            }
}

// ---------------- causal flash attention, load-balanced (Br=64 pairs, Bc=64) ----------
__global__ __launch_bounds__(256)
void attn_kernel(const unsigned short* __restrict__ q,
                 const unsigned short* __restrict__ k,
                 const unsigned short* __restrict__ vt,
                 unsigned short* __restrict__ ao) {
    __shared__ unsigned short Ks[64 * 128];
    __shared__ unsigned short Vts[128 * 64];
    __shared__ unsigned short Pw[4][16 * 72];

    const int t    = threadIdx.x;
    const int lane = t & 63, w = t >> 6;
    const int l15  = lane & 15, quad = lane >> 4;
    const int j    = blockIdx.x;
    const int bh   = blockIdx.y;
    const int b    = bh >> 4, h = bh & 15;
    const int qt[2] = {31 - j, j};

    const size_t hoff  = (size_t)h * D_;
    const size_t bbase = (size_t)b * T_ * DM_;

    short8 qa[2][4];
    for (int rs = 0; rs < 2; ++rs) {
        const int qw = qt[rs] * 64 + w * 16;
        const unsigned short* qp = q + bbase + (size_t)(qw + l15) * DM_ + hoff + quad * 8;
        for (int ds = 0; ds < 4; ++ds)
            qa[rs][ds] = *(const short8*)(qp + ds * 32);
    }

    floatx4 o[2][8];
    floatx4 lacc[2];
    for (int rs = 0; rs < 2; ++rs) {
        for (int c = 0; c < 8; ++c) o[rs][c] = (floatx4){0.f, 0.f, 0.f, 0.f};
        lacc[rs] = (floatx4){0.f, 0.f, 0.f, 0.f};
    }
    const unsigned short one_bf = 0x3F80;
    short8 ones;
    for (int i = 0; i < 8; ++i) ones[i] = (short)one_bf;

    const float kS = 0.08838834764831845f;
    const int ktend = qt[0];

    for (int kt = 0; kt <= ktend; ++kt) {
        if (kt) __syncthreads();
        for (int i = 0; i < 4; ++i) {
            int it = w * 4 + i;
            int krow = it * 4 + (lane >> 4);
            int gck  = ((lane & 15) ^ (krow & 7));
            gld16(k + bbase + (size_t)(kt * 64 + krow) * DM_ + hoff + gck * 8,
                  (unsigned short*)Ks + it * 512);
            int vrow = it * 8 + (lane >> 3);
            int gcv  = ((lane & 7) ^ (vrow & 7));
            gld16(vt + ((size_t)bh * 128 + vrow) * T_ + kt * 64 + gcv * 8,
                  (unsigned short*)Vts + it * 512);
        }
        __syncthreads();

        for (int rs = 0; rs < 2; ++rs) {
            const int kd = qt[rs];
            if (kt > kd) continue;
            const int qw = qt[rs] * 64 + w * 16;

            floatx4 s[4];
            for (int f = 0; f < 4; ++f) s[f] = (floatx4){0.f, 0.f, 0.f, 0.f};
            for (int ds = 0; ds < 4; ++ds)
                for (int f = 0; f < 4; ++f) {
                    int krow = f * 16 + l15;
                    int phys = (ds * 4 + quad) ^ (krow & 7);
                    short8 bf = *(const short8*)(Ks + krow * 128 + phys * 8);
                    s[f] = __builtin_amdgcn_mfma_f32_16x16x32_bf16(qa[rs][ds], bf, s[f], 0, 0, 0);
                }

            const bool diag = (kt == kd);
            for (int r = 0; r < 4; ++r) {
                int qrow = qw + quad * 4 + r;
                for (int f = 0; f < 4; ++f) {
                    float x = s[f][r] * kS;
                    float e = __expf(x);
                    if (diag && (kt * 64 + f * 16 + l15 > qrow)) e = 0.f;
                    Pw[w][(quad * 4 + r) * 72 + f * 16 + l15] = f2bf(e);
                }
            }

            short8 pa0 = *(const short8*)(&Pw[w][l15 * 72 + quad * 8]);
            short8 pa1 = *(const short8*)(&Pw[w][l15 * 72 + 32 + quad * 8]);
            lacc[rs] = __builtin_amdgcn_mfma_f32_16x16x32_bf16(pa0, ones, lacc[rs], 0, 0, 0);
            lacc[rs] = __builtin_amdgcn_mfma_f32_16x16x32_bf16(pa1, ones, lacc[rs], 0, 0, 0);
            for (int c = 0; c < 8; ++c) {
                int vrow = c * 16 + l15;
                short8 b0 = *(const short8*)(Vts + vrow * 64 + ((quad) ^ (vrow & 7)) * 8);
                short8 b1 = *(const short8*)(Vts + vrow * 64 + ((4 + quad) ^ (vrow & 7)) * 8);
                o[rs][c] = __builtin_amdgcn_mfma_f32_16x16x32_bf16(pa0, b0, o[rs][c], 0, 0, 0);
                o[rs][c] = __builtin_amdgcn_mfma_f32_16x16x32_bf16(pa1, b1, o[rs][c], 0, 0, 0);
            }
        }
    }

    for (int rs = 0; rs < 2; ++rs) {
        const int qw = qt[rs] * 64 + w * 16;
        for (int r = 0; r < 4; ++r) {
            float inv = 1.0f / lacc[rs][r];
            int qrow = qw + quad * 4 + r;
            size_t obase = bbase + (size_t)qrow * DM_ + hoff;
            for (int c = 0; c < 8; ++c)
                ao[obase + c * 16 + l15] = f2bf(o[rs][c][r] * inv);
        }
    }
}

extern "C" void kernel_launch(void* const* d_in, const int* in_sizes, int n_in,
                              void* d_out, int out_size, void* d_ws, size_t ws_size,
                              hipStream_t stream) {
    const float* x    = (const float*)d_in[0];
    const float* wq   = (const float*)d_in[1];
    const float* wk   = (const float*)d_in[2];
    const float* wv   = (const float*)d_in[3];
    const float* wo   = (const float*)d_in[4];
    const float* cosT = (const float*)d_in[5];
    const float* sinT = (const float*)d_in[6];
    float* out = (float*)d_out;

    const size_t NX = (size_t)B_ * T_ * DM_;
    const size_t NW = (size_t)DM_ * DM_;

    unsigned short* xb  = (unsigned short*)d_ws;
    unsigned short* wqb = xb + NX;
    unsigned short* wob = wqb + 3 * NW;
    unsigned short* qb  = wob + NW;
    unsigned short* kb  = qb + NX;
    unsigned short* vtb = kb + NX;
    unsigned short* aob = vtb + NX;

    conv_all<<<dim3((int)(NW / 4 / 256), 6), 256, 0, stream>>>(
        x, wq, wk, wv, wo, xb, wqb, (int)(NW / 4));

    gemm_qkv<<<dim3(24, 32), 512, 0, stream>>>(xb, wqb, qb, kb, vtb, cosT, sinT);

    attn_kernel<<<dim3(16, B_ * H_), 256, 0, stream>>>(qb, kb, vtb, aob);

    gemm_bt<<<dim3(16, 32), 256, 0, stream>>>(aob, wob, out, B_ * T_, DM_, DM_);
}